// Round 7
// baseline (697.869 us; speedup 1.0000x reference)
//
#include <hip/hip_runtime.h>

#define VOCAB 50257
#define NB 512
#define NT 2048
#define NOUT 128
#define L2E 1.4426950408889634f

__device__ __forceinline__ float sig_s(float xs){   // arg pre-scaled by log2e
    return __builtin_amdgcn_rcpf(1.0f + __builtin_amdgcn_exp2f(-xs));
}
__device__ __forceinline__ float tanh_s2(float xs2){ // arg pre-scaled by 2*log2e
    return fmaf(-2.0f, __builtin_amdgcn_rcpf(1.0f + __builtin_amdgcn_exp2f(xs2)), 1.0f);
}
__device__ __forceinline__ float tanh_n(float x){    // natural arg (tanh(c))
    return fmaf(-2.0f, __builtin_amdgcn_rcpf(1.0f + __builtin_amdgcn_exp2f(2.8853900817779268f*x)), 1.0f);
}

// K1: tab[v][k][g] = s(j)*(b0[j] + emb[v]·Wih0[j]),  j=2g+k, g∈{i,f,g,o}
__global__ __launch_bounds__(256) void build_table(const float* __restrict__ emb,
                                                   const float* __restrict__ Wih0,
                                                   const float* __restrict__ b0,
                                                   float* __restrict__ tab){
    int v = blockIdx.x*256 + threadIdx.x;
    if (v >= VOCAB) return;
    const float4* ep = (const float4*)(emb + (size_t)v*8);
    float4 e0 = ep[0], e1 = ep[1];
    float e[8] = {e0.x,e0.y,e0.z,e0.w,e1.x,e1.y,e1.z,e1.w};
    float o[8];
#pragma unroll
    for (int j=0;j<8;j++){
        float s = b0[j];
#pragma unroll
        for (int d=0;d<8;d++) s = fmaf(e[d], Wih0[j*8+d], s);
        o[j] = s * ((j==4||j==5) ? 2.0f*L2E : L2E);
    }
    float4* tp = (float4*)(tab + (size_t)v*8);
    tp[0] = make_float4(o[0],o[2],o[4],o[6]);  // k=0: (i0,f0,g0,o0)
    tp[1] = make_float4(o[1],o[3],o[5],o[7]);  // k=1: (i1,f1,g1,o1)
}

// K1b: gx[t][b][k] = tab[x[b][t]][k]  — massively parallel gather on all CUs.
__global__ __launch_bounds__(256) void expand_gates(const int* __restrict__ x,
                                                    const float* __restrict__ tab,
                                                    float4* __restrict__ gx){
    int gid = blockIdx.x*256 + threadIdx.x;   // [0, B*T)
    int t = gid >> 9;
    int b = gid & (NB-1);
    int tok = x[(size_t)b*NT + t];
    const float4* tp = (const float4*)tab + (size_t)tok*2;
    float4 v0 = tp[0], v1 = tp[1];
    gx[(size_t)gid*2]   = v0;
    gx[(size_t)gid*2+1] = v1;
}

// K2a: layer-0 scan only. 2 lanes/row, 16 blocks x 64 = 16 waves.
// Writes h0 stream [T][B][2] (coalesced) + h_n[0], c_n[0].
__global__ __launch_bounds__(64) void lstm_l0(const float4* __restrict__ gx,
                                              const float* __restrict__ Whh0,
                                              float* __restrict__ h0w,     // [T][B][2]
                                              float* __restrict__ tail){
    const int tid = threadIdx.x;
    const int k = tid & 1;
    const int row = blockIdx.x*32 + (tid>>1);
    float w00[4], w01[4];
#pragma unroll
    for (int g=0; g<4; g++){
        int j = 2*g+k;
        float s = (j==4||j==5) ? 2.0f*L2E : L2E;
        w00[g]=Whh0[j*2+k]*s;  w01[g]=Whh0[j*2+(k^1)]*s;
    }
    const size_t S = (size_t)NB*2;             // float4 stride per t
    const float4* __restrict__ gp = gx + (size_t)row*2 + k;
    float h0=0.f, c0=0.f;
    float4 fA = gp[0*S], fB = gp[1*S], fC = gp[2*S], fD = gp[3*S];

#define STEP0(F, T, PFT) { \
    float4 nf = gp[(size_t)(PFT)*S]; \
    float ho = __shfl_xor(h0,1); \
    float ai = fmaf(w00[0],h0, fmaf(w01[0],ho, F.x)); \
    float af = fmaf(w00[1],h0, fmaf(w01[1],ho, F.y)); \
    float ag = fmaf(w00[2],h0, fmaf(w01[2],ho, F.z)); \
    float ao = fmaf(w00[3],h0, fmaf(w01[3],ho, F.w)); \
    float si=sig_s(ai), sf=sig_s(af), tg=tanh_s2(ag), so=sig_s(ao); \
    c0 = fmaf(sf,c0, si*tg); \
    h0 = so*tanh_n(c0); \
    h0w[((size_t)(T)*NB + row)*2 + k] = h0; \
    F = nf; }

    for (int t=0; t<NT; t+=4){
        STEP0(fA, t+0, t+4)
        STEP0(fB, t+1, t+5)
        STEP0(fC, t+2, t+6)
        STEP0(fD, t+3, t+7)   // prefetch ≤ gx[NT+3]: inside d_out scratch, unused values
    }
#undef STEP0
    tail[row*2+k]          = h0;   // h_n[0]
    tail[2*NB*2 + row*2+k] = c0;   // c_n[0]
}

// K2b: layer-1 scan only. Reads h0 stream (float2/lane — both elements arrive,
// so no input shuffle; only h1o needs a DPP shuffle). Writes y1 + h_n[1], c_n[1].
__global__ __launch_bounds__(64) void lstm_l1(const float2* __restrict__ h0s,  // [T][B]
                                              const float* __restrict__ Wih1,
                                              const float* __restrict__ Whh1,
                                              const float* __restrict__ b1,
                                              float* __restrict__ y1out,       // [T][B][2]
                                              float* __restrict__ tail){
    const int tid = threadIdx.x;
    const int k = tid & 1;
    const int row = blockIdx.x*32 + (tid>>1);
    float wiA[4], wiB[4], wh0[4], wh1[4], bg[4];
#pragma unroll
    for (int g=0; g<4; g++){
        int j = 2*g+k;
        float s = (j==4||j==5) ? 2.0f*L2E : L2E;
        wiA[g]=Wih1[j*2+0]*s;  wiB[g]=Wih1[j*2+1]*s;     // multiply F.x / F.y directly
        wh0[g]=Whh1[j*2+k]*s;  wh1[g]=Whh1[j*2+(k^1)]*s;
        bg[g]=b1[j]*s;
    }
    const float2* __restrict__ hp = h0s + row;
    float h1=0.f, c1=0.f;
    float2 fA = hp[0*NB], fB = hp[1*NB], fC = hp[2*NB], fD = hp[3*NB];

#define STEP1(F, T, PFT) { \
    float2 nf = hp[(size_t)(PFT)*NB]; \
    float h1o = __shfl_xor(h1,1); \
    float q0 = fmaf(wh0[0],h1, fmaf(wh1[0],h1o, fmaf(wiA[0],F.x, fmaf(wiB[0],F.y, bg[0])))); \
    float q1 = fmaf(wh0[1],h1, fmaf(wh1[1],h1o, fmaf(wiA[1],F.x, fmaf(wiB[1],F.y, bg[1])))); \
    float q2 = fmaf(wh0[2],h1, fmaf(wh1[2],h1o, fmaf(wiA[2],F.x, fmaf(wiB[2],F.y, bg[2])))); \
    float q3 = fmaf(wh0[3],h1, fmaf(wh1[3],h1o, fmaf(wiA[3],F.x, fmaf(wiB[3],F.y, bg[3])))); \
    float ti=sig_s(q0), tf=sig_s(q1), th=tanh_s2(q2), to=sig_s(q3); \
    c1 = fmaf(tf,c1, ti*th); \
    h1 = to*tanh_n(c1); \
    y1out[((size_t)(T)*NB + row)*2 + k] = h1; \
    F = nf; }

    for (int t=0; t<NT; t+=4){
        STEP1(fA, t+0, t+4)
        STEP1(fB, t+1, t+5)
        STEP1(fC, t+2, t+6)
        STEP1(fD, t+3, t+7)   // prefetch ≤ h0s[NT+3]: inside d_out scratch, unused
    }
#undef STEP1
    tail[NB*2 + row*2+k]   = h1;   // h_n[1]
    tail[3*NB*2 + row*2+k] = c1;   // c_n[1]
}

// K3: out[bt][j] = y1[bt]·Wfc[j] + bfc[j]; one float4 store per thread.
__global__ __launch_bounds__(256) void fc_out(const float* __restrict__ y1,
                                              const float* __restrict__ Wfc,
                                              const float* __restrict__ bfc,
                                              float* __restrict__ out){
    const int tid = threadIdx.x;
    const int j4  = tid & 31;
    const int btl = tid >> 5;
    const int bt  = blockIdx.x*8 + btl;
    const int b   = bt >> 11;
    const int tt  = bt & (NT-1);
    const float2 y  = *(const float2*)(y1 + ((size_t)tt*NB + b)*2);
    const float4 wa = *(const float4*)(Wfc + j4*8);
    const float4 wb = *(const float4*)(Wfc + j4*8+4);
    const float4 bbv= *(const float4*)(bfc + j4*4);
    float4 o;
    o.x = fmaf(y.x,wa.x, fmaf(y.y,wa.y, bbv.x));
    o.y = fmaf(y.x,wa.z, fmaf(y.y,wa.w, bbv.y));
    o.z = fmaf(y.x,wb.x, fmaf(y.y,wb.y, bbv.z));
    o.w = fmaf(y.x,wb.z, fmaf(y.y,wb.w, bbv.w));
    *(float4*)(out + (size_t)bt*128 + j4*4) = o;
}

extern "C" void kernel_launch(void* const* d_in, const int* in_sizes, int n_in,
                              void* d_out, int out_size, void* d_ws, size_t ws_size,
                              hipStream_t stream){
    const int*   x    = (const int*)d_in[0];
    const float* emb  = (const float*)d_in[1];
    const float* Wih0 = (const float*)d_in[2];
    const float* Whh0 = (const float*)d_in[3];
    const float* b0   = (const float*)d_in[4];
    const float* Wih1 = (const float*)d_in[5];
    const float* Whh1 = (const float*)d_in[6];
    const float* b1   = (const float*)d_in[7];
    const float* Wfc  = (const float*)d_in[8];
    const float* bfc  = (const float*)d_in[9];
    float* out  = (float*)d_out;
    float* tab  = (float*)d_ws;                       // VOCAB*8 floats = 1.6 MB
    float* y1   = tab + (size_t)VOCAB*8;              // T*B*2 floats = 8 MB (ws)
    float* tail = out + (size_t)NB*NT*NOUT;           // h_n|c_n region of d_out
    // scratch inside d_out (fully overwritten by fc_out afterwards):
    float4* gxs = (float4*)d_out;                     // [T+4][B][2] float4 = 32 MB + pad
    float*  h0s = out + (size_t)9000000;              // 36 MB offset: [T+4][B][2] floats = 8 MB + pad

    build_table<<<(VOCAB+255)/256, 256, 0, stream>>>(emb, Wih0, b0, tab);
    expand_gates<<<(NB*NT)/256, 256, 0, stream>>>(x, tab, gxs);
    lstm_l0<<<16, 64, 0, stream>>>(gxs, Whh0, h0s, tail);
    lstm_l1<<<16, 64, 0, stream>>>((const float2*)h0s, Wih1, Whh1, b1, y1, tail);
    fc_out<<<(NB*NT)/8, 256, 0, stream>>>(y1, Wfc, bfc, out);
}

// Round 8
// 400.128 us; speedup vs baseline: 1.7441x; 1.7441x over previous
//
#include <hip/hip_runtime.h>

#define VOCAB 50257
#define NB 512
#define NT 2048
#define NOUT 128
#define CHUNK 32
#define L2E 1.4426950408889634f

__device__ __forceinline__ float sig_s(float xs){   // arg pre-scaled by log2e
    return __builtin_amdgcn_rcpf(1.0f + __builtin_amdgcn_exp2f(-xs));
}
__device__ __forceinline__ float tanh_s2(float xs2){ // arg pre-scaled by 2*log2e
    return fmaf(-2.0f, __builtin_amdgcn_rcpf(1.0f + __builtin_amdgcn_exp2f(xs2)), 1.0f);
}
__device__ __forceinline__ float tanh_n(float x){    // natural arg (tanh(c))
    return fmaf(-2.0f, __builtin_amdgcn_rcpf(1.0f + __builtin_amdgcn_exp2f(2.8853900817779268f*x)), 1.0f);
}

// K1: tab[v][k][g] = s(j)*(b0[j] + emb[v]·Wih0[j]),  j=2g+k
__global__ __launch_bounds__(256) void build_table(const float* __restrict__ emb,
                                                   const float* __restrict__ Wih0,
                                                   const float* __restrict__ b0,
                                                   float* __restrict__ tab){
    int v = blockIdx.x*256 + threadIdx.x;
    if (v >= VOCAB) return;
    const float4* ep = (const float4*)(emb + (size_t)v*8);
    float4 e0 = ep[0], e1 = ep[1];
    float e[8] = {e0.x,e0.y,e0.z,e0.w,e1.x,e1.y,e1.z,e1.w};
    float o[8];
#pragma unroll
    for (int j=0;j<8;j++){
        float s = b0[j];
#pragma unroll
        for (int d=0;d<8;d++) s = fmaf(e[d], Wih0[j*8+d], s);
        o[j] = s * ((j==4||j==5) ? 2.0f*L2E : L2E);
    }
    float4* tp = (float4*)(tab + (size_t)v*8);
    tp[0] = make_float4(o[0],o[2],o[4],o[6]);  // k=0: (i0,f0,g0,o0)
    tp[1] = make_float4(o[1],o[3],o[5],o[7]);  // k=1
}

// K1b: gx[t][b][k] = tab[x[b][t]][k]  — massively parallel gather on all CUs.
__global__ __launch_bounds__(256) void expand_gates(const int* __restrict__ x,
                                                    const float* __restrict__ tab,
                                                    float4* __restrict__ gx){
    int gid = blockIdx.x*256 + threadIdx.x;   // [0, B*T)
    int t = gid >> 9;
    int b = gid & (NB-1);
    int tok = x[(size_t)b*NT + t];
    const float4* tp = (const float4*)tab + (size_t)tok*2;
    float4 v0 = tp[0], v1 = tp[1];
    gx[(size_t)gid*2]   = v0;
    gx[(size_t)gid*2+1] = v1;
}

// K2: layer-pipelined scan. Block = 128 threads = 2 waves on 2 SIMDs.
// wave0 = layer 0 (reads gx, produces h0 chunks into LDS);
// wave1 = layer 1 (consumes LDS chunk c-1, writes y1). One barrier per chunk.
__global__ __launch_bounds__(128) void lstm_pipe(const float4* __restrict__ gx,
                                                 const float* __restrict__ Whh0,
                                                 const float* __restrict__ Wih1,
                                                 const float* __restrict__ Whh1,
                                                 const float* __restrict__ b1,
                                                 float* __restrict__ y1out,   // [T][B][2]
                                                 float* __restrict__ tail){
    __shared__ float h0buf[2][CHUNK][32][2];   // 16 KB double buffer
    const int tid  = threadIdx.x;
    const int wv   = tid >> 6;
    const int lane = tid & 63;
    const int k    = lane & 1;
    const int lrow = lane >> 1;                // 0..31
    const int row  = blockIdx.x*32 + lrow;

    float w00[4], w01[4];                      // wave0
    float wiA[4], wiB[4], wh0[4], wh1[4], bg[4]; // wave1
    if (wv == 0){
#pragma unroll
        for (int g=0; g<4; g++){
            int j = 2*g+k;
            float s = (j==4||j==5) ? 2.0f*L2E : L2E;
            w00[g]=Whh0[j*2+k]*s;  w01[g]=Whh0[j*2+(k^1)]*s;
        }
    } else {
#pragma unroll
        for (int g=0; g<4; g++){
            int j = 2*g+k;
            float s = (j==4||j==5) ? 2.0f*L2E : L2E;
            wiA[g]=Wih1[j*2+0]*s;  wiB[g]=Wih1[j*2+1]*s;
            wh0[g]=Whh1[j*2+k]*s;  wh1[g]=Whh1[j*2+(k^1)]*s;
            bg[g]=b1[j]*s;
        }
    }
    const size_t S = (size_t)NB*2;             // float4 stride per t
    const float4* __restrict__ gp = gx + (size_t)row*2 + k;
    float hA=0.f, cA=0.f;                      // layer-0 state (wave0)
    float hB=0.f, cB=0.f;                      // layer-1 state (wave1)
    float4 fA, fB, fC, fD;
    if (wv==0){ fA=gp[0*S]; fB=gp[1*S]; fC=gp[2*S]; fD=gp[3*S]; }

    for (int c=0; c<=NT/CHUNK; ++c){
        if (wv==0){
            if (c < NT/CHUNK){
                const int buf = c & 1;
                const int base = c*CHUNK;
#define PSTEP(F, SS) { \
    float4 nf = gp[(size_t)(base+(SS)+4)*S]; /* ≤ gx[NT+3]: in-bounds scratch */ \
    float ho = __shfl_xor(hA,1); \
    float ai = fmaf(w00[0],hA, fmaf(w01[0],ho, F.x)); \
    float af = fmaf(w00[1],hA, fmaf(w01[1],ho, F.y)); \
    float ag = fmaf(w00[2],hA, fmaf(w01[2],ho, F.z)); \
    float ao = fmaf(w00[3],hA, fmaf(w01[3],ho, F.w)); \
    float si=sig_s(ai), sf=sig_s(af), tg=tanh_s2(ag), so=sig_s(ao); \
    cA = fmaf(sf,cA, si*tg); \
    hA = so*tanh_n(cA); \
    h0buf[buf][SS][lrow][k] = hA; \
    F = nf; }
                for (int s=0; s<CHUNK; s+=4){
                    PSTEP(fA, s+0)
                    PSTEP(fB, s+1)
                    PSTEP(fC, s+2)
                    PSTEP(fD, s+3)
                }
#undef PSTEP
            }
        } else {
            if (c >= 1){
                const int buf = (c-1) & 1;
                const int base = (c-1)*CHUNK;
#pragma unroll 4
                for (int s=0; s<CHUNK; ++s){
                    const float2 hv = *(const float2*)&h0buf[buf][s][lrow][0];
                    float h1o = __shfl_xor(hB,1);
                    float q0 = fmaf(wh0[0],hB, fmaf(wh1[0],h1o, fmaf(wiA[0],hv.x, fmaf(wiB[0],hv.y, bg[0]))));
                    float q1 = fmaf(wh0[1],hB, fmaf(wh1[1],h1o, fmaf(wiA[1],hv.x, fmaf(wiB[1],hv.y, bg[1]))));
                    float q2 = fmaf(wh0[2],hB, fmaf(wh1[2],h1o, fmaf(wiA[2],hv.x, fmaf(wiB[2],hv.y, bg[2]))));
                    float q3 = fmaf(wh0[3],hB, fmaf(wh1[3],h1o, fmaf(wiA[3],hv.x, fmaf(wiB[3],hv.y, bg[3]))));
                    float ti=sig_s(q0), tf=sig_s(q1), th=tanh_s2(q2), to=sig_s(q3);
                    cB = fmaf(tf,cB, ti*th);
                    hB = to*tanh_n(cB);
                    y1out[((size_t)(base+s)*NB + row)*2 + k] = hB;
                }
            }
        }
        __syncthreads();   // uniform across both waves, 65 total
    }
    if (wv==0){
        tail[row*2+k]          = hA;   // h_n[0]
        tail[2*NB*2 + row*2+k] = cA;   // c_n[0]
    } else {
        tail[NB*2 + row*2+k]   = hB;   // h_n[1]
        tail[3*NB*2 + row*2+k] = cB;   // c_n[1]
    }
}

// K3: out[bt][j] = y1[bt]·Wfc[j] + bfc[j]; one float4 store per thread.
__global__ __launch_bounds__(256) void fc_out(const float* __restrict__ y1,
                                              const float* __restrict__ Wfc,
                                              const float* __restrict__ bfc,
                                              float* __restrict__ out){
    const int tid = threadIdx.x;
    const int j4  = tid & 31;
    const int btl = tid >> 5;
    const int bt  = blockIdx.x*8 + btl;
    const int b   = bt >> 11;
    const int tt  = bt & (NT-1);
    const float2 y  = *(const float2*)(y1 + ((size_t)tt*NB + b)*2);
    const float4 wa = *(const float4*)(Wfc + j4*8);
    const float4 wb = *(const float4*)(Wfc + j4*8+4);
    const float4 bbv= *(const float4*)(bfc + j4*4);
    float4 o;
    o.x = fmaf(y.x,wa.x, fmaf(y.y,wa.y, bbv.x));
    o.y = fmaf(y.x,wa.z, fmaf(y.y,wa.w, bbv.y));
    o.z = fmaf(y.x,wb.x, fmaf(y.y,wb.y, bbv.z));
    o.w = fmaf(y.x,wb.z, fmaf(y.y,wb.w, bbv.w));
    *(float4*)(out + (size_t)bt*128 + j4*4) = o;
}

extern "C" void kernel_launch(void* const* d_in, const int* in_sizes, int n_in,
                              void* d_out, int out_size, void* d_ws, size_t ws_size,
                              hipStream_t stream){
    const int*   x    = (const int*)d_in[0];
    const float* emb  = (const float*)d_in[1];
    const float* Wih0 = (const float*)d_in[2];
    const float* Whh0 = (const float*)d_in[3];
    const float* b0   = (const float*)d_in[4];
    const float* Wih1 = (const float*)d_in[5];
    const float* Whh1 = (const float*)d_in[6];
    const float* b1   = (const float*)d_in[7];
    const float* Wfc  = (const float*)d_in[8];
    const float* bfc  = (const float*)d_in[9];
    float* out  = (float*)d_out;
    float* tab  = (float*)d_ws;                       // VOCAB*8 floats = 1.6 MB (ws)
    float* y1   = tab + (size_t)VOCAB*8;              // T*B*2 floats = 8 MB (ws)
    float* tail = out + (size_t)NB*NT*NOUT;           // h_n|c_n region of d_out
    float4* gxs = (float4*)d_out;                     // 32 MB scratch in d_out; dead before fc_out writes

    build_table<<<(VOCAB+255)/256, 256, 0, stream>>>(emb, Wih0, b0, tab);
    expand_gates<<<(NB*NT)/256, 256, 0, stream>>>(x, tab, gxs);
    lstm_pipe<<<16, 128, 0, stream>>>(gxs, Whh0, Wih1, Whh1, b1, y1, tail);
    fc_out<<<(NB*NT)/8, 256, 0, stream>>>(y1, Wfc, bfc, out);
}

// Round 9
// 297.347 us; speedup vs baseline: 2.3470x; 1.3457x over previous
//
#include <hip/hip_runtime.h>

#define VOCAB 50257
#define NB 512
#define NT 2048
#define NOUT 128
#define CHUNK 32
#define L2E 1.4426950408889634f

#define QP_XOR1 0xB1   // quad_perm [1,0,3,2]
#define QP_PAIR 0xA0   // quad_perm [0,0,2,2]
#define QP_CROSS 0x0A  // quad_perm [2,2,0,0]

template<int CTRL>
__device__ __forceinline__ float qp(float v){
    return __int_as_float(__builtin_amdgcn_update_dpp(0, __float_as_int(v), CTRL, 0xF, 0xF, true));
}

// K1: tab[v][p], p=0..7 -> gate rows perm={i0,f0,g0,o0,i1,f1,g1,o1} with folded
// scale: -log2e for sigmoid rows (i,f,o), +2log2e for tanh rows (g).
__global__ __launch_bounds__(256) void build_table(const float* __restrict__ emb,
                                                   const float* __restrict__ Wih0,
                                                   const float* __restrict__ b0,
                                                   float* __restrict__ tab){
    int v = blockIdx.x*256 + threadIdx.x;
    if (v >= VOCAB) return;
    const float4* ep = (const float4*)(emb + (size_t)v*8);
    float4 e0 = ep[0], e1 = ep[1];
    float e[8] = {e0.x,e0.y,e0.z,e0.w,e1.x,e1.y,e1.z,e1.w};
    const int perm[8] = {0,2,4,6,1,3,5,7};
    float o[8];
#pragma unroll
    for (int p=0;p<8;p++){
        int rj = perm[p];
        float s = b0[rj];
#pragma unroll
        for (int d=0;d<8;d++) s = fmaf(e[d], Wih0[rj*8+d], s);
        o[p] = s * ((rj==4||rj==5) ? 2.0f*L2E : -L2E);
    }
    float4* tp = (float4*)(tab + (size_t)v*8);
    tp[0] = make_float4(o[0],o[1],o[2],o[3]);
    tp[1] = make_float4(o[4],o[5],o[6],o[7]);
}

// K1b: gx[t][b][0..7] = tab[x[b][t]][0..7] — parallel gather on all CUs.
__global__ __launch_bounds__(256) void expand_gates(const int* __restrict__ x,
                                                    const float* __restrict__ tab,
                                                    float4* __restrict__ gx){
    int gid = blockIdx.x*256 + threadIdx.x;   // [0, B*T)
    int t = gid >> 9;
    int b = gid & (NB-1);
    int tok = x[(size_t)b*NT + t];
    const float4* tp = (const float4*)tab + (size_t)tok*2;
    float4 v0 = tp[0], v1 = tp[1];
    gx[(size_t)gid*2]   = v0;
    gx[(size_t)gid*2+1] = v1;
}

// Uniform gate nonlinearity + quad combine. Lane l of each quad holds 2 pre-acts:
// l0:(i0,f0) l1:(g0,o0) l2:(i1,f1) l3:(g1,o1), args pre-scaled so
// value = A + B*rcp(1+exp2(x)). Valid c/h live on lanes 0,2; broadcast via DPP.
#define GATE_COMBINE(x0, x1) { \
    float ex0 = __builtin_amdgcn_exp2f(x0); \
    float ex1 = __builtin_amdgcn_exp2f(x1); \
    float r0 = __builtin_amdgcn_rcpf(1.0f+ex0); \
    float r1 = __builtin_amdgcn_rcpf(1.0f+ex1); \
    float v0 = fmaf(B0, r0, A0); \
    float u0 = qp<QP_XOR1>(v0); \
    float u1 = qp<QP_XOR1>(r1); \
    c = fmaf(r1, c, v0*u0); \
    float e2c = __builtin_amdgcn_exp2f(2.0f*L2E*c); \
    float th = fmaf(-2.0f, __builtin_amdgcn_rcpf(1.0f+e2c), 1.0f); \
    float hh = u1*th; \
    hs = qp<QP_PAIR>(hh); \
    ho = qp<QP_CROSS>(hh); }

// K2: layer-pipelined scan, 4 lanes/row. Block = 128 thr = 2 waves;
// wave0 = layer0 (gx -> LDS h0 chunks), wave1 = layer1 (LDS -> y1).
__global__ __launch_bounds__(128) void lstm_pipe(const float2* __restrict__ gx,
                                                 const float* __restrict__ Whh0,
                                                 const float* __restrict__ Wih1,
                                                 const float* __restrict__ Whh1,
                                                 const float* __restrict__ b1,
                                                 float* __restrict__ y1out,   // [T][B][2]
                                                 float* __restrict__ tail){
    __shared__ float h0buf[2][CHUNK][16][2];   // 8 KB double buffer
    const int tid  = threadIdx.x;
    const int wv   = tid >> 6;
    const int lane = tid & 63;
    const int l    = lane & 3;
    const int lrow = lane >> 2;               // 0..15
    const int row  = blockIdx.x*16 + lrow;
    const int e    = l >> 1;                  // element this pair serves
    const int rj0  = (l&1)*4 + e;             // gate row of value 0 (i or g)
    const int rj1  = rj0 + 2;                 // gate row of value 1 (f or o)
    const float s0 = (l&1) ? 2.0f*L2E : -L2E;
    const float s1 = -L2E;
    const float A0 = (l&1) ? 1.0f : 0.0f;
    const float B0 = (l&1) ? -2.0f : 1.0f;

    // wave0 weights (layer 0)
    const float wS0 = Whh0[rj0*2+e]*s0,  wO0 = Whh0[rj0*2+(e^1)]*s0;
    const float wS1 = Whh0[rj1*2+e]*s1,  wO1 = Whh0[rj1*2+(e^1)]*s1;
    // wave1 weights (layer 1)
    const float wi00 = Wih1[rj0*2+0]*s0, wi01 = Wih1[rj0*2+1]*s0;
    const float wi10 = Wih1[rj1*2+0]*s1, wi11 = Wih1[rj1*2+1]*s1;
    const float whS0 = Whh1[rj0*2+e]*s0, whO0 = Whh1[rj0*2+(e^1)]*s0;
    const float whS1 = Whh1[rj1*2+e]*s1, whO1 = Whh1[rj1*2+(e^1)]*s1;
    const float bb0  = b1[rj0]*s0,       bb1  = b1[rj1]*s1;

    float hs=0.f, ho=0.f, c=0.f;
    const size_t ST = (size_t)NB*4;           // float2 stride per t
    const float2* __restrict__ gp = gx + (size_t)row*4 + l;
    float2 f0,f1,f2,f3,f4,f5,f6,f7;
    if (wv==0){
        f0=gp[0*ST]; f1=gp[1*ST]; f2=gp[2*ST]; f3=gp[3*ST];
        f4=gp[4*ST]; f5=gp[5*ST]; f6=gp[6*ST]; f7=gp[7*ST];
    }

    for (int cidx=0; cidx<=NT/CHUNK; ++cidx){
        if (wv==0){
            if (cidx < NT/CHUNK){
                const int buf = cidx & 1;
                const int base = cidx*CHUNK;
#define PSTEP(F, SS) { \
    float2 nf = gp[(size_t)(base+(SS)+8)*ST]; /* <= gx[NT+7]: in-bounds scratch, unused values */ \
    float x0 = fmaf(wS0,hs, fmaf(wO0,ho, F.x)); \
    float x1 = fmaf(wS1,hs, fmaf(wO1,ho, F.y)); \
    GATE_COMBINE(x0, x1) \
    h0buf[buf][SS][lrow][e] = hs; \
    F = nf; }
                for (int s=0; s<CHUNK; s+=8){
                    PSTEP(f0,s+0) PSTEP(f1,s+1) PSTEP(f2,s+2) PSTEP(f3,s+3)
                    PSTEP(f4,s+4) PSTEP(f5,s+5) PSTEP(f6,s+6) PSTEP(f7,s+7)
                }
#undef PSTEP
            }
        } else {
            if (cidx >= 1){
                const int buf = (cidx-1) & 1;
                const int base = (cidx-1)*CHUNK;
#pragma unroll 8
                for (int s=0; s<CHUNK; ++s){
                    const float2 h0v = *(const float2*)&h0buf[buf][s][lrow][0];
                    float x0 = fmaf(whS0,hs, fmaf(whO0,ho, fmaf(wi00,h0v.x, fmaf(wi01,h0v.y, bb0))));
                    float x1 = fmaf(whS1,hs, fmaf(whO1,ho, fmaf(wi10,h0v.x, fmaf(wi11,h0v.y, bb1))));
                    GATE_COMBINE(x0, x1)
                    y1out[((size_t)(base+s)*NB + row)*2 + e] = hs;
                }
            }
        }
        __syncthreads();
    }
    const float cs = qp<QP_PAIR>(c);          // valid c lives on lanes 0,2
    if (wv==0){
        tail[row*2+e]          = hs;   // h_n[0]
        tail[2*NB*2 + row*2+e] = cs;   // c_n[0]
    } else {
        tail[NB*2 + row*2+e]   = hs;   // h_n[1]
        tail[3*NB*2 + row*2+e] = cs;   // c_n[1]
    }
}

// K3: out[bt][j] = y1[bt]·Wfc[j] + bfc[j]; one float4 store per thread.
__global__ __launch_bounds__(256) void fc_out(const float* __restrict__ y1,
                                              const float* __restrict__ Wfc,
                                              const float* __restrict__ bfc,
                                              float* __restrict__ out){
    const int tid = threadIdx.x;
    const int j4  = tid & 31;
    const int btl = tid >> 5;
    const int bt  = blockIdx.x*8 + btl;
    const int b   = bt >> 11;
    const int tt  = bt & (NT-1);
    const float2 y  = *(const float2*)(y1 + ((size_t)tt*NB + b)*2);
    const float4 wa = *(const float4*)(Wfc + j4*8);
    const float4 wb = *(const float4*)(Wfc + j4*8+4);
    const float4 bbv= *(const float4*)(bfc + j4*4);
    float4 o;
    o.x = fmaf(y.x,wa.x, fmaf(y.y,wa.y, bbv.x));
    o.y = fmaf(y.x,wa.z, fmaf(y.y,wa.w, bbv.y));
    o.z = fmaf(y.x,wb.x, fmaf(y.y,wb.y, bbv.z));
    o.w = fmaf(y.x,wb.z, fmaf(y.y,wb.w, bbv.w));
    *(float4*)(out + (size_t)bt*128 + j4*4) = o;
}

extern "C" void kernel_launch(void* const* d_in, const int* in_sizes, int n_in,
                              void* d_out, int out_size, void* d_ws, size_t ws_size,
                              hipStream_t stream){
    const int*   x    = (const int*)d_in[0];
    const float* emb  = (const float*)d_in[1];
    const float* Wih0 = (const float*)d_in[2];
    const float* Whh0 = (const float*)d_in[3];
    const float* b0   = (const float*)d_in[4];
    const float* Wih1 = (const float*)d_in[5];
    const float* Whh1 = (const float*)d_in[6];
    const float* b1   = (const float*)d_in[7];
    const float* Wfc  = (const float*)d_in[8];
    const float* bfc  = (const float*)d_in[9];
    float* out  = (float*)d_out;
    float* tab  = (float*)d_ws;                       // VOCAB*8 floats = 1.6 MB (ws)
    float* y1   = tab + (size_t)VOCAB*8;              // T*B*2 floats = 8 MB (ws)
    float* tail = out + (size_t)NB*NT*NOUT;           // h_n|c_n region of d_out
    float4* gxs = (float4*)d_out;                     // 33.6 MB scratch in d_out; dead before fc_out writes

    build_table<<<(VOCAB+255)/256, 256, 0, stream>>>(emb, Wih0, b0, tab);
    expand_gates<<<(NB*NT)/256, 256, 0, stream>>>(x, tab, gxs);
    lstm_pipe<<<32, 128, 0, stream>>>((const float2*)gxs, Whh0, Wih1, Whh1, b1, y1, tail);
    fc_out<<<(NB*NT)/8, 256, 0, stream>>>(y1, Wfc, bfc, out);
}